// Round 2
// baseline (838.748 us; speedup 1.0000x reference)
//
#include <hip/hip_runtime.h>
#include <hip/hip_bf16.h>
#include <math.h>

#define HD 128
#define NN 50000
#define NE 500000
#define LN_EPS 1e-5f

typedef __attribute__((ext_vector_type(8))) short short8;
typedef __attribute__((ext_vector_type(4))) float f32x4;

__device__ __forceinline__ unsigned short f2bf(float f) {
    unsigned int u = __float_as_uint(f);
    u = (u + 0x7FFFu + ((u >> 16) & 1u)) >> 16;   // RNE truncate to bf16
    return (unsigned short)u;
}
__device__ __forceinline__ float bf2f(unsigned short b) {
    return __uint_as_float(((unsigned int)b) << 16);
}
__device__ __forceinline__ float gelu_f(float x) {
    return 0.5f * x * (1.0f + erff(x * 0.70710678118654752440f));
}
__device__ __forceinline__ float sigm_f(float x) {
    return 1.0f / (1.0f + __expf(-x));
}

// ---------------------------------------------------------------------------
// K1: node_pre — X = h (N x128) @ [src_W | e1_Wa | e1_Wb] (128 x 384) + bias
//     persistent grid: B-fragments loaded ONCE per block, grid-stride over M.
// ---------------------------------------------------------------------------
__global__ __launch_bounds__(384) void node_pre_kernel(
    const float* __restrict__ h,
    const float* __restrict__ src_W, const float* __restrict__ src_b,
    const float* __restrict__ e1_W, const float* __restrict__ e1_b,
    unsigned short* __restrict__ hswb,
    unsigned short* __restrict__ a1b,
    unsigned short* __restrict__ b1b)
{
    const int lane = threadIdx.x & 63;
    const int w = threadIdx.x >> 6;           // 0..5
    const int lo = lane & 15, hi = lane >> 4;

    short8 bf[4][4];
    #pragma unroll
    for (int nn = 0; nn < 4; ++nn) {
        const int c = w * 64 + nn * 16 + lo;   // 0..383
        #pragma unroll
        for (int kk = 0; kk < 4; ++kk) {
            short8 v;
            #pragma unroll
            for (int j = 0; j < 8; ++j) {
                const int k = kk * 32 + hi * 8 + j;
                float wv;
                if (c < 128)      wv = src_W[k * 128 + c];
                else if (c < 256) wv = e1_W[k * 128 + (c - 128)];
                else              wv = e1_W[(128 + k) * 128 + (c - 256)];
                v[j] = (short)f2bf(wv);
            }
            bf[kk][nn] = v;
        }
    }

    for (int m0 = blockIdx.x * 64; m0 < NN; m0 += gridDim.x * 64) {
        f32x4 acc[4][4];
        #pragma unroll
        for (int mm = 0; mm < 4; ++mm)
            #pragma unroll
            for (int nn = 0; nn < 4; ++nn)
                acc[mm][nn] = (f32x4){0.f, 0.f, 0.f, 0.f};

        #pragma unroll
        for (int mm = 0; mm < 4; ++mm) {
            int row = m0 + mm * 16 + lo;
            if (row >= NN) row = NN - 1;
            short8 af[4];
            #pragma unroll
            for (int kk = 0; kk < 4; ++kk) {
                const float* p = h + row * 128 + kk * 32 + hi * 8;
                const float4 q0 = *(const float4*)p;
                const float4 q1 = *(const float4*)(p + 4);
                short8 v;
                v[0] = (short)f2bf(q0.x); v[1] = (short)f2bf(q0.y);
                v[2] = (short)f2bf(q0.z); v[3] = (short)f2bf(q0.w);
                v[4] = (short)f2bf(q1.x); v[5] = (short)f2bf(q1.y);
                v[6] = (short)f2bf(q1.z); v[7] = (short)f2bf(q1.w);
                af[kk] = v;
            }
            #pragma unroll
            for (int nn = 0; nn < 4; ++nn)
                #pragma unroll
                for (int kk = 0; kk < 4; ++kk)
                    acc[mm][nn] = __builtin_amdgcn_mfma_f32_16x16x32_bf16(
                        af[kk], bf[kk][nn], acc[mm][nn], 0, 0, 0);
        }

        #pragma unroll
        for (int mm = 0; mm < 4; ++mm) {
            #pragma unroll
            for (int nn = 0; nn < 4; ++nn) {
                const int c = w * 64 + nn * 16 + lo;
                #pragma unroll
                for (int r = 0; r < 4; ++r) {
                    const int row = m0 + mm * 16 + hi * 4 + r;
                    if (row < NN) {
                        const float v = acc[mm][nn][r];
                        if (c < 128)      hswb[row * 128 + c]       = f2bf(v + src_b[c]);
                        else if (c < 256) a1b [row * 128 + (c-128)] = f2bf(v + e1_b[c-128]);
                        else              b1b [row * 128 + (c-256)] = f2bf(v);
                    }
                }
            }
        }
    }
}

// ---------------------------------------------------------------------------
// Sort machinery: histogram -> 1-block scan -> scatter (counting sort by dst)
// ---------------------------------------------------------------------------
__global__ __launch_bounds__(256) void hist_kernel(
    const int* __restrict__ edge_index, int* __restrict__ deg)
{
    const int e = blockIdx.x * 256 + threadIdx.x;
    if (e < NE) atomicAdd(&deg[edge_index[2 * e + 1]], 1);
}

__global__ __launch_bounds__(1024) void scan_kernel(
    const int* __restrict__ deg, int* __restrict__ cursor)
{
    __shared__ int sums[1024];
    const int t = threadIdx.x;
    const int chunk = (NN + 1023) / 1024;   // 49
    const int i0 = t * chunk;
    int s = 0;
    for (int i = 0; i < chunk; ++i) {
        const int idx = i0 + i;
        if (idx < NN) s += deg[idx];
    }
    sums[t] = s;
    __syncthreads();
    for (int off = 1; off < 1024; off <<= 1) {
        const int v = (t >= off) ? sums[t - off] : 0;
        __syncthreads();
        sums[t] += v;
        __syncthreads();
    }
    int run = (t > 0) ? sums[t - 1] : 0;    // exclusive prefix of this chunk
    for (int i = 0; i < chunk; ++i) {
        const int idx = i0 + i;
        if (idx < NN) {
            cursor[idx] = run;
            run += deg[idx];
        }
    }
}

__global__ __launch_bounds__(256) void scatter_kernel(
    const int* __restrict__ edge_index, int* __restrict__ cursor,
    int* __restrict__ sorted_eid)
{
    const int e = blockIdx.x * 256 + threadIdx.x;
    if (e < NE) {
        const int d = edge_index[2 * e + 1];
        const int pos = atomicAdd(&cursor[d], 1);
        sorted_eid[pos] = e;
    }
}

// ---------------------------------------------------------------------------
// K3: edge kernel over dst-SORTED edges, 64-edge tiles.
//   phase A (vector): t = a1[src]+b1[dst]+ea@e1_Wc; hid=gelu(t) -> LDS (swizzled)
//   phase B (MFMA):   ctx = hid @ e2_W  (B-fragments persistent in registers)
//   epilogue:         msg -> LDS agg_tile[lid][c] (ds_add), lid = local dst id
//   flush:            ~ndist*128 coalesced global atomics per tile
// ---------------------------------------------------------------------------
__global__ __launch_bounds__(256, 2) void edge_kernel(
    const float* __restrict__ edge_attr, const int* __restrict__ edge_index,
    const int* __restrict__ sorted_eid,
    const float* __restrict__ e1_W, const float* __restrict__ e2_W, const float* __restrict__ e2_b,
    const unsigned short* __restrict__ hswb,
    const unsigned short* __restrict__ a1b, const unsigned short* __restrict__ b1b,
    float* __restrict__ agg, int nblocks)
{
    __shared__ unsigned int hid32[64 * 64];   // 64 rows x 128 bf16, 16B-chunk XOR swizzle
    __shared__ float agg_tile[64 * 128];      // per-local-dst accumulator
    __shared__ int src_lds[64];
    __shared__ int dst_lds[64];
    __shared__ int lid_lds[64];
    __shared__ int gdst_lds[64];
    __shared__ int ndist_lds;

    const int lane = threadIdx.x & 63;
    const int w = __builtin_amdgcn_readfirstlane(threadIdx.x >> 6);  // 0..3
    const int lo = lane & 15, hi = lane >> 4;

    // e1_W edge-attr columns for this lane's two hid cols
    float e1c0[16], e1c1[16];
    #pragma unroll
    for (int k = 0; k < 16; ++k) {
        e1c0[k] = e1_W[(256 + k) * 128 + 2 * lane];
        e1c1[k] = e1_W[(256 + k) * 128 + 2 * lane + 1];
    }

    // e2_W B-fragments: wave w n-tiles {w*32, w*32+16, 128+w*32, 128+w*32+16}
    short8 bf[4][4];
    #pragma unroll
    for (int nn = 0; nn < 4; ++nn) {
        const int nbase = (nn < 2) ? (w * 32 + nn * 16) : (128 + w * 32 + (nn - 2) * 16);
        const int n = nbase + lo;
        #pragma unroll
        for (int kk = 0; kk < 4; ++kk) {
            short8 v;
            #pragma unroll
            for (int j = 0; j < 8; ++j) {
                const int k = kk * 32 + hi * 8 + j;
                v[j] = (short)f2bf(e2_W[k * 256 + n]);
            }
            bf[kk][nn] = v;
        }
    }
    float bg[2], bs[2];
    #pragma unroll
    for (int nn = 0; nn < 2; ++nn) {
        bg[nn] = e2_b[w * 32 + nn * 16 + lo];
        bs[nn] = e2_b[128 + w * 32 + nn * 16 + lo];
    }

    // zero the LDS accumulator once (flush re-zeros what it reads)
    for (int i = threadIdx.x; i < 64 * 128; i += 256) agg_tile[i] = 0.f;

    for (int eb = blockIdx.x; eb < nblocks; eb += gridDim.x) {
        // ---- phase A ----
        for (int ee = 0; ee < 16; ++ee) {
            const int er = w * 16 + ee;
            const int ti = eb * 64 + er;
            if (ti < NE) {
                const int eid = sorted_eid[ti];
                const int s = edge_index[2 * eid];
                const int d = edge_index[2 * eid + 1];
                if (lane == 0) { src_lds[er] = s; dst_lds[er] = d; }
                const unsigned int av = *(const unsigned int*)(a1b + s * 128 + 2 * lane);
                const unsigned int bv = *(const unsigned int*)(b1b + d * 128 + 2 * lane);
                float t0 = bf2f((unsigned short)(av & 0xFFFFu)) + bf2f((unsigned short)(bv & 0xFFFFu));
                float t1 = bf2f((unsigned short)(av >> 16))     + bf2f((unsigned short)(bv >> 16));
                const float4 q0 = *(const float4*)(edge_attr + eid * 16);
                const float4 q1 = *(const float4*)(edge_attr + eid * 16 + 4);
                const float4 q2 = *(const float4*)(edge_attr + eid * 16 + 8);
                const float4 q3 = *(const float4*)(edge_attr + eid * 16 + 12);
                const float ea[16] = {q0.x,q0.y,q0.z,q0.w, q1.x,q1.y,q1.z,q1.w,
                                      q2.x,q2.y,q2.z,q2.w, q3.x,q3.y,q3.z,q3.w};
                #pragma unroll
                for (int k = 0; k < 16; ++k) {
                    t0 += ea[k] * e1c0[k];
                    t1 += ea[k] * e1c1[k];
                }
                t0 = gelu_f(t0);
                t1 = gelu_f(t1);
                const unsigned int hv = (unsigned int)f2bf(t0) | ((unsigned int)f2bf(t1) << 16);
                const int chunk = (lane >> 2) ^ (er & 7);     // swizzle 16B chunks
                hid32[er * 64 + chunk * 4 + (lane & 3)] = hv;
            } else if (lane == 0) {
                dst_lds[er] = -1;
            }
        }
        __syncthreads();   // B1

        // ---- wave 0: local-dst-id scan over the 64 sorted rows ----
        if (w == 0) {
            const int er = lane;
            const int d = dst_lds[er];
            const bool valid = (eb * 64 + er < NE);
            const bool flag = valid && (er == 0 || dst_lds[er - 1] != d);
            const unsigned long long mask = __ballot(flag ? 1 : 0);
            const unsigned long long below =
                (er == 63) ? mask : (mask & ((1ull << (er + 1)) - 1ull));
            const int lid = (int)__popcll(below) - 1;
            lid_lds[er] = lid;
            if (flag) gdst_lds[lid] = d;
            if (er == 0) ndist_lds = (int)__popcll(mask);
        }

        // ---- phase B: 64 MFMA per wave ----
        f32x4 acc[4][4];
        #pragma unroll
        for (int mm = 0; mm < 4; ++mm)
            #pragma unroll
            for (int nn = 0; nn < 4; ++nn)
                acc[mm][nn] = (f32x4){0.f, 0.f, 0.f, 0.f};

        #pragma unroll
        for (int mm = 0; mm < 4; ++mm) {
            const int row = mm * 16 + lo;
            short8 af[4];
            #pragma unroll
            for (int kk = 0; kk < 4; ++kk) {
                const int sb = ((kk * 4 + hi) ^ (row & 7)) << 4;
                af[kk] = *(const short8*)((const char*)hid32 + row * 256 + sb);
            }
            #pragma unroll
            for (int nn = 0; nn < 4; ++nn)
                #pragma unroll
                for (int kk = 0; kk < 4; ++kk)
                    acc[mm][nn] = __builtin_amdgcn_mfma_f32_16x16x32_bf16(
                        af[kk], bf[kk][nn], acc[mm][nn], 0, 0, 0);
        }
        __syncthreads();   // B2: lid/gdst visible; hid32 free for next tile

        // ---- epilogue: msg -> LDS agg_tile with in-thread run compaction ----
        #pragma unroll
        for (int mm = 0; mm < 4; ++mm) {
            #pragma unroll
            for (int nn = 0; nn < 2; ++nn) {
                const int c = w * 32 + nn * 16 + lo;
                float pend = 0.f;
                int plid = -1;
                #pragma unroll
                for (int r = 0; r < 4; ++r) {
                    const int er = mm * 16 + hi * 4 + r;
                    if (eb * 64 + er < NE) {
                        const int s = src_lds[er];
                        const float g  = acc[mm][nn][r]     + bg[nn];
                        const float sh = acc[mm][nn + 2][r] + bs[nn];
                        const float msg = sigm_f(g) * bf2f(hswb[s * 128 + c]) + sh;
                        const int lid = lid_lds[er];
                        if (lid != plid) {
                            if (plid >= 0) atomicAdd(&agg_tile[plid * 128 + c], pend);
                            plid = lid; pend = 0.f;
                        }
                        pend += msg;
                    }
                }
                if (plid >= 0) atomicAdd(&agg_tile[plid * 128 + c], pend);
            }
        }
        __syncthreads();   // B3

        // ---- flush: coalesced global atomics, one per (distinct dst, col) ----
        const int nd = ndist_lds;
        for (int i = threadIdx.x; i < nd * 128; i += 256) {
            const float v = agg_tile[i];
            agg_tile[i] = 0.f;
            unsafeAtomicAdd(&agg[gdst_lds[i >> 7] * 128 + (i & 127)], v);
        }
        // no barrier needed here: next epilogue is after next B1+B2
    }
}

// ---------------------------------------------------------------------------
// K4: node_post — update = [h | agg/deg] (N x 256) @ [self_W; agg_W] + biases
//     x = h + gelu(update); LayerNorm(x) -> out.  Persistent grid.
// ---------------------------------------------------------------------------
__global__ __launch_bounds__(256) void node_post_kernel(
    const float* __restrict__ h,
    const float* __restrict__ self_W, const float* __restrict__ self_b,
    const float* __restrict__ agg_W, const float* __restrict__ agg_b,
    const float* __restrict__ ln_g, const float* __restrict__ ln_b,
    const float* __restrict__ agg, const int* __restrict__ deg,
    float* __restrict__ out)
{
    __shared__ float x_lds[64 * 129];
    const int lane = threadIdx.x & 63;
    const int w = threadIdx.x >> 6;          // 0..3
    const int lo = lane & 15, hi = lane >> 4;

    short8 bf[8][2];
    #pragma unroll
    for (int nn = 0; nn < 2; ++nn) {
        const int c = w * 32 + nn * 16 + lo;
        #pragma unroll
        for (int kk = 0; kk < 8; ++kk) {
            short8 v;
            #pragma unroll
            for (int j = 0; j < 8; ++j) {
                const int k = kk * 32 + hi * 8 + j;
                const float wv = (k < 128) ? self_W[k * 128 + c] : agg_W[(k - 128) * 128 + c];
                v[j] = (short)f2bf(wv);
            }
            bf[kk][nn] = v;
        }
    }

    for (int m0 = blockIdx.x * 64; m0 < NN; m0 += gridDim.x * 64) {
        f32x4 acc[4][2];
        #pragma unroll
        for (int mm = 0; mm < 4; ++mm)
            #pragma unroll
            for (int nn = 0; nn < 2; ++nn)
                acc[mm][nn] = (f32x4){0.f, 0.f, 0.f, 0.f};

        #pragma unroll
        for (int mm = 0; mm < 4; ++mm) {
            int row = m0 + mm * 16 + lo;
            if (row >= NN) row = NN - 1;
            const float rdeg = 1.0f / fmaxf((float)deg[row], 1.0f);
            short8 af[8];
            #pragma unroll
            for (int kk = 0; kk < 4; ++kk) {
                const float* p = h + row * 128 + kk * 32 + hi * 8;
                const float4 q0 = *(const float4*)p;
                const float4 q1 = *(const float4*)(p + 4);
                short8 v;
                v[0] = (short)f2bf(q0.x); v[1] = (short)f2bf(q0.y);
                v[2] = (short)f2bf(q0.z); v[3] = (short)f2bf(q0.w);
                v[4] = (short)f2bf(q1.x); v[5] = (short)f2bf(q1.y);
                v[6] = (short)f2bf(q1.z); v[7] = (short)f2bf(q1.w);
                af[kk] = v;
            }
            #pragma unroll
            for (int kk = 4; kk < 8; ++kk) {
                const float* p = agg + row * 128 + (kk - 4) * 32 + hi * 8;
                const float4 q0 = *(const float4*)p;
                const float4 q1 = *(const float4*)(p + 4);
                short8 v;
                v[0] = (short)f2bf(q0.x * rdeg); v[1] = (short)f2bf(q0.y * rdeg);
                v[2] = (short)f2bf(q0.z * rdeg); v[3] = (short)f2bf(q0.w * rdeg);
                v[4] = (short)f2bf(q1.x * rdeg); v[5] = (short)f2bf(q1.y * rdeg);
                v[6] = (short)f2bf(q1.z * rdeg); v[7] = (short)f2bf(q1.w * rdeg);
                af[kk] = v;
            }
            #pragma unroll
            for (int nn = 0; nn < 2; ++nn)
                #pragma unroll
                for (int kk = 0; kk < 8; ++kk)
                    acc[mm][nn] = __builtin_amdgcn_mfma_f32_16x16x32_bf16(
                        af[kk], bf[kk][nn], acc[mm][nn], 0, 0, 0);
        }

        #pragma unroll
        for (int mm = 0; mm < 4; ++mm) {
            #pragma unroll
            for (int nn = 0; nn < 2; ++nn) {
                const int c = w * 32 + nn * 16 + lo;
                const float bsum = self_b[c] + agg_b[c];
                #pragma unroll
                for (int r = 0; r < 4; ++r) {
                    const int rl = mm * 16 + hi * 4 + r;
                    int row = m0 + rl;
                    if (row >= NN) row = NN - 1;
                    const float upd = acc[mm][nn][r] + bsum;
                    x_lds[rl * 129 + c] = h[row * 128 + c] + gelu_f(upd);
                }
            }
        }
        __syncthreads();

        const int rrow = threadIdx.x >> 2;
        const int part = threadIdx.x & 3;
        float sum = 0.f, ss = 0.f;
        #pragma unroll
        for (int i = 0; i < 32; ++i) {
            const float v = x_lds[rrow * 129 + part * 32 + i];
            sum += v; ss += v * v;
        }
        sum += __shfl_xor(sum, 1); ss += __shfl_xor(ss, 1);
        sum += __shfl_xor(sum, 2); ss += __shfl_xor(ss, 2);
        const float mu = sum * (1.0f / 128.0f);
        const float var = ss * (1.0f / 128.0f) - mu * mu;
        const float rstd = rsqrtf(var + LN_EPS);
        const int grow = m0 + rrow;
        if (grow < NN) {
            #pragma unroll
            for (int i = 0; i < 32; ++i) {
                const int c = part * 32 + i;
                const float v = x_lds[rrow * 129 + c];
                out[grow * 128 + c] = (v - mu) * rstd * ln_g[c] + ln_b[c];
            }
        }
        __syncthreads();
    }
}

// ---------------------------------------------------------------------------
extern "C" void kernel_launch(void* const* d_in, const int* in_sizes, int n_in,
                              void* d_out, int out_size, void* d_ws, size_t ws_size,
                              hipStream_t stream) {
    const float* h         = (const float*)d_in[0];
    const float* edge_attr = (const float*)d_in[1];
    const int*   edge_index= (const int*)  d_in[2];
    const float* src_W     = (const float*)d_in[3];
    const float* src_b     = (const float*)d_in[4];
    const float* e1_W      = (const float*)d_in[5];
    const float* e1_b      = (const float*)d_in[6];
    const float* e2_W      = (const float*)d_in[7];
    const float* e2_b      = (const float*)d_in[8];
    const float* self_W    = (const float*)d_in[9];
    const float* self_b    = (const float*)d_in[10];
    const float* agg_W     = (const float*)d_in[11];
    const float* agg_b     = (const float*)d_in[12];
    const float* ln_g      = (const float*)d_in[13];
    const float* ln_b      = (const float*)d_in[14];
    float* out = (float*)d_out;

    char* ws = (char*)d_ws;
    unsigned short* hswb = (unsigned short*)(ws);               // N*128 bf16
    unsigned short* a1b  = (unsigned short*)(ws + 12800000);    // N*128 bf16
    unsigned short* b1b  = (unsigned short*)(ws + 25600000);    // N*128 bf16
    float* agg        = (float*)(ws + 38400000);                // N*128 f32 = 25.6 MB
    int*   deg        = (int*)  (ws + 64000000);                // N int
    int*   cursor     = (int*)  (ws + 64200000);                // N int
    int*   sorted_eid = (int*)  (ws + 64400000);                // E int

    // zero agg + deg (contiguous)
    hipMemsetAsync(agg, 0, 25600000 + 200000, stream);

    node_pre_kernel<<<256, 384, 0, stream>>>(
        h, src_W, src_b, e1_W, e1_b, hswb, a1b, b1b);

    hist_kernel<<<(NE + 255) / 256, 256, 0, stream>>>(edge_index, deg);
    scan_kernel<<<1, 1024, 0, stream>>>(deg, cursor);
    scatter_kernel<<<(NE + 255) / 256, 256, 0, stream>>>(edge_index, cursor, sorted_eid);

    const int nblocks = (NE + 63) / 64;   // 7813
    edge_kernel<<<1024, 256, 0, stream>>>(
        edge_attr, edge_index, sorted_eid, e1_W, e2_W, e2_b,
        hswb, a1b, b1b, agg, nblocks);

    node_post_kernel<<<256, 256, 0, stream>>>(
        h, self_W, self_b, agg_W, agg_b, ln_g, ln_b, agg, deg, out);
}